// Round 10
// baseline (277.612 us; speedup 1.0000x reference)
//
#include <hip/hip_runtime.h>
#include <cstdint>
#include <cstddef>

typedef __bf16 bf16x8 __attribute__((ext_vector_type(8)));
typedef __bf16 bf16x2 __attribute__((ext_vector_type(2)));
typedef float f32x4 __attribute__((ext_vector_type(4)));
typedef unsigned short u16x2 __attribute__((ext_vector_type(2)));

constexpr int HH = 1024;   // hidden dim
constexpr int II = 1024;   // intermediate dim
constexpr int KMAX = 2;
constexpr int EMAX = 8;
constexpr int GU_TILES = 40;   // M=64 tiles: worst case 32 + 8
constexpr int DN_TILES = 40;
constexpr float FALPHA = 1.702f;
constexpr float FLIMIT = 7.0f;

#if __has_builtin(__builtin_amdgcn_cvt_scalef32_pk_bf16_fp4)
#define USE_CVT 1
#else
#define USE_CVT 0
#endif

#define SCHED0() __builtin_amdgcn_sched_barrier(0)

// ---- fallback perm decode (k-order within 8-group permuted [0,2,4,6,1,3,5,7]) ----
__device__ __forceinline__ unsigned pk_add16(unsigned a, unsigned b) {
  u16x2 x, y;
  __builtin_memcpy(&x, &a, 4); __builtin_memcpy(&y, &b, 4);
  u16x2 r = x + y;
  unsigned o; __builtin_memcpy(&o, &r, 4); return o;
}
__device__ __forceinline__ int4 decode_chunk(int4 raw, unsigned addk) {
  unsigned p = (unsigned)raw.x | ((unsigned)raw.y << 8) |
               ((unsigned)raw.z << 16) | ((unsigned)raw.w << 24);
  unsigned q = p >> 4;
  unsigned me = p & 0x07070707u, mo = q & 0x07070707u;
  unsigned se = p & 0x08080808u, so = q & 0x08080808u;
  unsigned hiE = __builtin_amdgcn_perm(0x40404040u, 0x3F3F3F14u, me) | (se << 4);
  unsigned hiO = __builtin_amdgcn_perm(0x40404040u, 0x3F3F3F14u, mo) | (so << 4);
  unsigned loE = __builtin_amdgcn_perm(0xC0804000u, 0xC0800000u, me);
  unsigned loO = __builtin_amdgcn_perm(0xC0804000u, 0xC0800000u, mo);
  int4 out;
  out.x = (int)pk_add16(__builtin_amdgcn_perm(hiE, loE, 0x05010400u), addk);
  out.y = (int)pk_add16(__builtin_amdgcn_perm(hiE, loE, 0x07030602u), addk);
  out.z = (int)pk_add16(__builtin_amdgcn_perm(hiO, loO, 0x05010400u), addk);
  out.w = (int)pk_add16(__builtin_amdgcn_perm(hiO, loO, 0x07030602u), addk);
  return out;
}
__device__ __forceinline__ unsigned make_addk(int s) {
  int k = s - 127;
  unsigned t = ((unsigned)(k << 7)) & 0xFFFFu;
  return t | (t << 16);
}

// raw chunk (8 fp4 as int32-per-byte) + e8m0 scale -> bf16x8 fragment
__device__ __forceinline__ bf16x8 decode_frag(int4 raw, int s) {
#if USE_CVT
  unsigned t0 = __builtin_amdgcn_perm((unsigned)raw.y, (unsigned)raw.x, 0x00000400u);
  unsigned t1 = __builtin_amdgcn_perm((unsigned)raw.w, (unsigned)raw.z, 0x00000400u);
  unsigned p  = __builtin_amdgcn_perm(t1, t0, 0x05040100u);
  float scf = __uint_as_float((unsigned)s << 23);
  bf16x2 a = __builtin_amdgcn_cvt_scalef32_pk_bf16_fp4(p, scf, 0);
  bf16x2 b = __builtin_amdgcn_cvt_scalef32_pk_bf16_fp4(p, scf, 1);
  bf16x2 c = __builtin_amdgcn_cvt_scalef32_pk_bf16_fp4(p, scf, 2);
  bf16x2 d = __builtin_amdgcn_cvt_scalef32_pk_bf16_fp4(p, scf, 3);
  bf16x8 r;
  r[0]=a[0]; r[1]=a[1]; r[2]=b[0]; r[3]=b[1]; r[4]=c[0]; r[5]=c[1]; r[6]=d[0]; r[7]=d[1];
  return r;
#else
  int4 d4 = decode_chunk(raw, make_addk(s));
  bf16x8 r; __builtin_memcpy(&r, &d4, 16);
  return r;
#endif
}

// bijective chunked XCD swizzle (m204)
__device__ __forceinline__ int xcd_swz(int wg, int nwg) {
  int q = nwg >> 3, r = nwg & 7;
  int xcd = wg & 7, pos = wg >> 3;
  return (xcd < r ? xcd * (q + 1) : r * (q + 1) + (xcd - r) * q) + pos;
}

// ---------------- fused prep + hs convert ----------------
// grid = nConvBlocks + 1; last block (1024 thr) does routing/lists/tiles,
// others convert hs fp32 -> bf16 (1024 8-elem groups each).
__global__ __launch_bounds__(1024) void prep_convert(
    const float* __restrict__ logits, const int* __restrict__ dk, int T, int E,
    float* __restrict__ route, float* __restrict__ tw,
    int* __restrict__ lists, int* __restrict__ counts,
    int* __restrict__ tabGU, int* __restrict__ tabDN,
    const float* __restrict__ hs, __bf16* __restrict__ hsb, int n8) {
  if ((int)blockIdx.x < (int)gridDim.x - 1) {
    int g = blockIdx.x * 1024 + threadIdx.x;
    if (g < n8) {
      const float4* p = (const float4*)hs + (size_t)g * 2;
      float4 a = p[0], b = p[1];
      bf16x8 r;
#if USE_CVT
      r[0] = (__bf16)a.x; r[1] = (__bf16)a.y; r[2] = (__bf16)a.z; r[3] = (__bf16)a.w;
      r[4] = (__bf16)b.x; r[5] = (__bf16)b.y; r[6] = (__bf16)b.z; r[7] = (__bf16)b.w;
#else
      r[0] = (__bf16)a.x; r[1] = (__bf16)a.z; r[2] = (__bf16)b.x; r[3] = (__bf16)b.z;
      r[4] = (__bf16)a.y; r[5] = (__bf16)a.w; r[6] = (__bf16)b.y; r[7] = (__bf16)b.w;
#endif
      *(bf16x8*)(hsb + (size_t)g * 8) = r;
    }
    return;
  }
  __shared__ unsigned char s_ti[1024];
  __shared__ int s_cnt[EMAX];
  int t = threadIdx.x;
  int kk = *dk; if (kk > KMAX) kk = KMAX; if (kk < 1) kk = 1;
  int EE = E > EMAX ? EMAX : E;
  if (t < T) {
    float v[EMAX]; bool used[EMAX];
    for (int e = 0; e < EE; ++e) { v[e] = logits[t * E + e]; used[e] = false; route[t * E + e] = 0.f; }
    float tv[KMAX]; int ti[KMAX];
    for (int j = 0; j < kk; ++j) {
      float best = -3.4e38f; int bi = 0;
      for (int e = 0; e < EE; ++e) if (!used[e] && v[e] > best) { best = v[e]; bi = e; }
      used[bi] = true; tv[j] = best; ti[j] = bi;
    }
    float mx = tv[0], ssum = 0.f, wj[KMAX];
    for (int j = 0; j < kk; ++j) { wj[j] = __expf(tv[j] - mx); ssum += wj[j]; }
    for (int j = 0; j < kk; ++j) {
      float wv = wj[j] / ssum;
      route[t * E + ti[j]] = wv;
      tw[t * kk + j] = wv;
    }
    s_ti[t] = (unsigned char)(ti[0] | ((kk > 1 ? ti[1] : 0xF) << 4));
  } else if (t < 1024) {
    s_ti[t] = 0xFF;
  }
  __syncthreads();
  int w = t >> 6, lane = t & 63;
  if (w < EE) {
    int e = w, cnt = 0;
    for (int base = 0; base < T; base += 64) {
      int tt = base + lane;
      int j = -1;
      if (tt < T) {
        int packed = s_ti[tt];
        if ((packed & 0xF) == e) j = 0;
        else if ((packed >> 4) == e) j = 1;
      }
      unsigned long long m = __ballot(j >= 0);
      if (j >= 0) {
        int pre = __popcll(m & ((1ull << lane) - 1ull));
        lists[e * T + cnt + pre] = (tt << 3) | j;
      }
      cnt += __popcll(m);
    }
    if (lane == 0) { counts[e] = cnt; s_cnt[e] = cnt; }
  }
  __syncthreads();
  if (t == 0) {
    int g = 0, d = 0;
    for (int e = 0; e < EE; ++e) {
      int c = s_cnt[e];
      for (int m = 0; m * 64 < c && g < GU_TILES; ++m) tabGU[g++] = (e << 16) | m;
      for (int m = 0; m * 64 < c && d < DN_TILES; ++m) tabDN[d++] = (e << 16) | m;
    }
    for (; g < GU_TILES; ++g) tabGU[g] = -1;
    for (; d < DN_TILES; ++d) tabDN[d] = -1;
  }
}

// ================= gate+up GEMM: reg-staged single-LDS-buffer 2-phase =================
// M=64 x N=32 (16 i x {gate,up}), BK=64, 128 thr = 2 waves, wave tile 32x32.
// Per step per wave: 6 global_load_dwordx4 -> regs (next+1), compute LDS (cur),
// vmcnt(6) -> ds_write (next). LDS ~14.6 KB -> 8 blocks/CU (VGPR-capped 16 waves).
__global__ __launch_bounds__(128, 4) void gemm_gate_up(
    const __bf16* __restrict__ hsb,
    const int* __restrict__ gblk, const int* __restrict__ gscl, const float* __restrict__ gbias,
    const int* __restrict__ ublk, const int* __restrict__ uscl, const float* __restrict__ ubias,
    const int* __restrict__ lists, const int* __restrict__ counts,
    const float* __restrict__ tw, const int* __restrict__ dk,
    const int* __restrict__ tab,
    __bf16* __restrict__ act, int T)
{
  int lin = xcd_swz(blockIdx.x, GU_TILES * (II / 16));
  int ntile = lin / GU_TILES, xt = lin % GU_TILES;
  int te = tab[xt];
  if (te < 0) return;
  int e = te >> 16, mtile = te & 0xFFFF;
  int cnt = counts[e];
  int n_valid = cnt - mtile * 64;
  if (n_valid <= 0) return;
  if (n_valid > 64) n_valid = 64;
  int kk = *dk; if (kk > KMAX) kk = KMAX; if (kk < 1) kk = 1;
  int ibase = ntile * 16;

  __shared__ int s_tok[64];
  __shared__ __attribute__((aligned(16))) char Abuf[8192];  // 64 rows x 128B, [row][c^(row&7)]
  __shared__ __attribute__((aligned(16))) char Braw[4096];  // 32 rows x 128B raw
  __shared__ __attribute__((aligned(8))) unsigned short sS[32][36];

  int tid = threadIdx.x;
  if (tid < 64) {
    int idx = mtile * 64 + tid;
    s_tok[tid] = lists[e * T + (idx < cnt ? idx : mtile * 64)];
  }
  __syncthreads();

  int lane = tid & 63, w = tid >> 6;
  int r15 = lane & 15, kg = lane >> 4;
  int cL = lane & 7, sub = lane >> 3;
  int cA = cL ^ sub;

  // A: wave w stages rows w*32 + q*8 + sub, q=0..3
  const char* aSrc[4]; int aLds[4];
  #pragma unroll
  for (int q = 0; q < 4; ++q) {
    int row = w * 32 + q * 8 + sub;
    int tok = s_tok[row] >> 3;
    aSrc[q] = (const char*)hsb + (size_t)tok * (HH * 2) + cL * 16;
    aLds[q] = row * 128 + (cA << 4);
  }
  // B: wave w stages rows w*16 + q*8 + sub, q=0..1; row->mat,(i)
  const char* bSrc[2]; int bLds[2];
  #pragma unroll
  for (int q = 0; q < 2; ++q) {
    int row = w * 16 + q * 8 + sub;
    int mat = (row >> 4) & 1;
    int i = ibase + (row & 15);
    const int* base = mat ? ublk : gblk;
    bSrc[q] = (const char*)(base + ((size_t)e * II + i) * (HH / 2)) + cL * 16;
    bLds[q] = row * 128 + (cA << 4);
  }

  // scale table: 32 rows x 8 chunks = 256 items, 2 per thread
  {
    int idx = tid;
    #pragma unroll
    for (int rep = 0; rep < 2; ++rep, idx += 128) {
      int row = idx >> 3, c4 = idx & 7;
      int mat = (row >> 4) & 1;
      int i = ibase + (row & 15);
      const int* sbase = mat ? uscl : gscl;
      int4 v = *((const int4*)(sbase + ((size_t)e * II + i) * 32) + c4);
      unsigned short* dst = &sS[row][c4 * 4];
      dst[0] = (unsigned short)v.x; dst[1] = (unsigned short)v.y;
      dst[2] = (unsigned short)v.z; dst[3] = (unsigned short)v.w;
    }
  }

  f32x4 acc[2][2];
  #pragma unroll
  for (int a = 0; a < 2; ++a) { acc[a][0] = (f32x4)0.f; acc[a][1] = (f32x4)0.f; }

  int4 rA0[4], rA1[4], rB0[2], rB1[2];
  // prologue: batch0 -> set0, batch1 -> set1
  #pragma unroll
  for (int q = 0; q < 4; ++q) rA0[q] = *(const int4*)(aSrc[q]);
  #pragma unroll
  for (int q = 0; q < 2; ++q) rB0[q] = *(const int4*)(bSrc[q]);
  #pragma unroll
  for (int q = 0; q < 4; ++q) rA1[q] = *(const int4*)(aSrc[q] + 128);
  #pragma unroll
  for (int q = 0; q < 2; ++q) rB1[q] = *(const int4*)(bSrc[q] + 128);
  asm volatile("s_waitcnt vmcnt(6)" ::: "memory");   // batch0 (+scale loads) done
  SCHED0();
  #pragma unroll
  for (int q = 0; q < 4; ++q) *(int4*)(Abuf + aLds[q]) = rA0[q];
  #pragma unroll
  for (int q = 0; q < 2; ++q) *(int4*)(Braw + bLds[q]) = rB0[q];
  asm volatile("s_waitcnt lgkmcnt(0)" ::: "memory");
  SCHED0();
  __builtin_amdgcn_s_barrier();

  constexpr int NK = HH / 64;  // 16

  auto compute = [&](int t) {
    unsigned sv0 = *(const unsigned*)((const char*)sS + (r15) * 72 + t * 4);
    unsigned sv1 = *(const unsigned*)((const char*)sS + (16 + r15) * 72 + t * 4);
    #pragma unroll
    for (int kq = 0; kq < 2; ++kq) {
      int kc = kq * 4 + kg;
      bf16x8 bfr[2];
      {
        int n0 = r15;
        int4 raw = *(const int4*)(Braw + n0 * 128 + ((kc ^ (n0 & 7)) << 4));
        bfr[0] = decode_frag(raw, kq ? (int)(sv0 >> 16) : (int)(sv0 & 0xFFFF));
        int n1 = 16 + r15;
        int4 raw1 = *(const int4*)(Braw + n1 * 128 + ((kc ^ (n1 & 7)) << 4));
        bfr[1] = decode_frag(raw1, kq ? (int)(sv1 >> 16) : (int)(sv1 & 0xFFFF));
      }
      #pragma unroll
      for (int fm = 0; fm < 2; ++fm) {
        int m = w * 32 + fm * 16 + r15;
        bf16x8 af = *(const bf16x8*)(Abuf + m * 128 + ((kc ^ (m & 7)) << 4));
        acc[fm][0] = __builtin_amdgcn_mfma_f32_16x16x32_bf16(af, bfr[0], acc[fm][0], 0, 0, 0);
        acc[fm][1] = __builtin_amdgcn_mfma_f32_16x16x32_bf16(af, bfr[1], acc[fm][1], 0, 0, 0);
      }
    }
  };

  #pragma unroll 1
  for (int tt = 0; tt < NK; tt += 2) {
    // ---- sub-step tt (even): LDS=batch tt, set1=batch tt+1 in flight ----
    compute(tt);
    __builtin_amdgcn_s_barrier();
    SCHED0();
    if (tt + 2 < NK) {
      #pragma unroll
      for (int q = 0; q < 4; ++q) rA0[q] = *(const int4*)(aSrc[q] + (tt + 2) * 128);
      #pragma unroll
      for (int q = 0; q < 2; ++q) rB0[q] = *(const int4*)(bSrc[q] + (tt + 2) * 128);
      asm volatile("s_waitcnt vmcnt(6)" ::: "memory");
    } else {
      asm volatile("s_waitcnt vmcnt(0)" ::: "memory");
    }
    SCHED0();
    #pragma unroll
    for (int q = 0; q < 4; ++q) *(int4*)(Abuf + aLds[q]) = rA1[q];
    #pragma unroll
    for (int q = 0; q < 2; ++q) *(int4*)(Braw + bLds[q]) = rB1[q];
    asm volatile("s_waitcnt lgkmcnt(0)" ::: "memory");
    SCHED0();
    __builtin_amdgcn_s_barrier();
    // ---- sub-step tt+1 (odd): LDS=batch tt+1, set0=batch tt+2 in flight ----
    compute(tt + 1);
    if (tt + 2 < NK) {
      __builtin_amdgcn_s_barrier();
      SCHED0();
      if (tt + 3 < NK) {
        #pragma unroll
        for (int q = 0; q < 4; ++q) rA1[q] = *(const int4*)(aSrc[q] + (tt + 3) * 128);
        #pragma unroll
        for (int q = 0; q < 2; ++q) rB1[q] = *(const int4*)(bSrc[q] + (tt + 3) * 128);
        asm volatile("s_waitcnt vmcnt(6)" ::: "memory");
      } else {
        asm volatile("s_waitcnt vmcnt(0)" ::: "memory");
      }
      SCHED0();
      #pragma unroll
      for (int q = 0; q < 4; ++q) *(int4*)(Abuf + aLds[q]) = rA0[q];
      #pragma unroll
      for (int q = 0; q < 2; ++q) *(int4*)(Braw + bLds[q]) = rB0[q];
      asm volatile("s_waitcnt lgkmcnt(0)" ::: "memory");
      SCHED0();
      __builtin_amdgcn_s_barrier();
    }
  }

  // epilogue: fn0 = gate, fn1 = up at i = ibase + r15
  {
    int i_log = ibase + r15;
    float gb = gbias[e * II + i_log], ub = ubias[e * II + i_log];
#if USE_CVT
    int i_st = i_log;
#else
    int i_st = (i_log & ~7) | ((i_log & 1) << 2) | ((i_log & 7) >> 1);
#endif
    #pragma unroll
    for (int fm = 0; fm < 2; ++fm) {
      #pragma unroll
      for (int rg = 0; rg < 4; ++rg) {
        int mloc = w * 32 + fm * 16 + kg * 4 + rg;
        if (mloc < n_valid) {
          int entry = s_tok[mloc];
          int t2 = entry >> 3, j = entry & 7;
          float wv = tw[t2 * kk + j];
          float g = fminf(acc[fm][0][rg] + gb, FLIMIT);
          float u = fminf(fmaxf(acc[fm][1][rg] + ub, -FLIMIT), FLIMIT);
          float glu = g / (1.f + __expf(-FALPHA * g));
          act[((size_t)t2 * kk + j) * II + i_st] = (__bf16)((u + 1.f) * glu * wv);
        }
      }
    }
  }
}

// ================= down GEMM: same structure =================
__global__ __launch_bounds__(128, 4) void gemm_down(
    const __bf16* __restrict__ act,
    const int* __restrict__ dblk, const int* __restrict__ dscl,
    const int* __restrict__ lists, const int* __restrict__ counts,
    const int* __restrict__ dk, const int* __restrict__ tab,
    __bf16* __restrict__ partial, int T)
{
  int lin = xcd_swz(blockIdx.x, DN_TILES * (HH / 32));
  int ntile = lin / DN_TILES, xt = lin % DN_TILES;
  int te = tab[xt];
  if (te < 0) return;
  int e = te >> 16, mtile = te & 0xFFFF;
  int cnt = counts[e];
  int n_valid = cnt - mtile * 64;
  if (n_valid <= 0) return;
  if (n_valid > 64) n_valid = 64;
  int kk = *dk; if (kk > KMAX) kk = KMAX; if (kk < 1) kk = 1;
  int hbase = ntile * 32;

  __shared__ int s_tok[64];
  __shared__ __attribute__((aligned(16))) char Abuf[8192];
  __shared__ __attribute__((aligned(16))) char Braw[4096];
  __shared__ __attribute__((aligned(8))) unsigned short sS[32][36];

  int tid = threadIdx.x;
  if (tid < 64) {
    int idx = mtile * 64 + tid;
    s_tok[tid] = lists[e * T + (idx < cnt ? idx : mtile * 64)];
  }
  __syncthreads();

  int lane = tid & 63, w = tid >> 6;
  int r15 = lane & 15, kg = lane >> 4;
  int cL = lane & 7, sub = lane >> 3;
  int cA = cL ^ sub;

  const char* aSrc[4]; int aLds[4];
  #pragma unroll
  for (int q = 0; q < 4; ++q) {
    int row = w * 32 + q * 8 + sub;
    int entry = s_tok[row];
    size_t slot = (size_t)(entry >> 3) * kk + (entry & 7);
    aSrc[q] = (const char*)act + slot * (II * 2) + cL * 16;
    aLds[q] = row * 128 + (cA << 4);
  }
  const char* bSrc[2]; int bLds[2];
  #pragma unroll
  for (int q = 0; q < 2; ++q) {
    int row = w * 16 + q * 8 + sub;
    bSrc[q] = (const char*)(dblk + ((size_t)e * HH + hbase + row) * (II / 2)) + cL * 16;
    bLds[q] = row * 128 + (cA << 4);
  }

  {
    int idx = tid;
    #pragma unroll
    for (int rep = 0; rep < 2; ++rep, idx += 128) {
      int row = idx >> 3, c4 = idx & 7;
      int4 v = *((const int4*)(dscl + ((size_t)e * HH + hbase + row) * 32) + c4);
      unsigned short* dst = &sS[row][c4 * 4];
      dst[0] = (unsigned short)v.x; dst[1] = (unsigned short)v.y;
      dst[2] = (unsigned short)v.z; dst[3] = (unsigned short)v.w;
    }
  }

  f32x4 acc[2][2];
  #pragma unroll
  for (int a = 0; a < 2; ++a) { acc[a][0] = (f32x4)0.f; acc[a][1] = (f32x4)0.f; }

  int4 rA0[4], rA1[4], rB0[2], rB1[2];
  #pragma unroll
  for (int q = 0; q < 4; ++q) rA0[q] = *(const int4*)(aSrc[q]);
  #pragma unroll
  for (int q = 0; q < 2; ++q) rB0[q] = *(const int4*)(bSrc[q]);
  #pragma unroll
  for (int q = 0; q < 4; ++q) rA1[q] = *(const int4*)(aSrc[q] + 128);
  #pragma unroll
  for (int q = 0; q < 2; ++q) rB1[q] = *(const int4*)(bSrc[q] + 128);
  asm volatile("s_waitcnt vmcnt(6)" ::: "memory");
  SCHED0();
  #pragma unroll
  for (int q = 0; q < 4; ++q) *(int4*)(Abuf + aLds[q]) = rA0[q];
  #pragma unroll
  for (int q = 0; q < 2; ++q) *(int4*)(Braw + bLds[q]) = rB0[q];
  asm volatile("s_waitcnt lgkmcnt(0)" ::: "memory");
  SCHED0();
  __builtin_amdgcn_s_barrier();

  constexpr int NK = II / 64;  // 16

  auto compute = [&](int t) {
    unsigned sv0 = *(const unsigned*)((const char*)sS + (r15) * 72 + t * 4);
    unsigned sv1 = *(const unsigned*)((const char*)sS + (16 + r15) * 72 + t * 4);
    #pragma unroll
    for (int kq = 0; kq < 2; ++kq) {
      int kc = kq * 4 + kg;
      bf16x8 bfr[2];
      {
        int n0 = r15;
        int4 raw = *(const int4*)(Braw + n0 * 128 + ((kc ^ (n0 & 7)) << 4));
        bfr[0] = decode_frag(raw, kq ? (int)(sv0 >> 16) : (int)(sv0 & 0xFFFF));
        int n1 = 16 + r15;
        int4 raw1 = *(const int4*)(Braw + n1 * 128 + ((kc ^ (n1 & 7)) << 4));
        bfr[1] = decode_frag(raw1, kq ? (int)(sv1 >> 16) : (int)(sv1 & 0xFFFF));
      }
      #pragma unroll
      for (int fm = 0; fm < 2; ++fm) {
        int m = w * 32 + fm * 16 + r15;
        bf16x8 af = *(const bf16x8*)(Abuf + m * 128 + ((kc ^ (m & 7)) << 4));
        acc[fm][0] = __builtin_amdgcn_mfma_f32_16x16x32_bf16(af, bfr[0], acc[fm][0], 0, 0, 0);
        acc[fm][1] = __builtin_amdgcn_mfma_f32_16x16x32_bf16(af, bfr[1], acc[fm][1], 0, 0, 0);
      }
    }
  };

  #pragma unroll 1
  for (int tt = 0; tt < NK; tt += 2) {
    compute(tt);
    __builtin_amdgcn_s_barrier();
    SCHED0();
    if (tt + 2 < NK) {
      #pragma unroll
      for (int q = 0; q < 4; ++q) rA0[q] = *(const int4*)(aSrc[q] + (tt + 2) * 128);
      #pragma unroll
      for (int q = 0; q < 2; ++q) rB0[q] = *(const int4*)(bSrc[q] + (tt + 2) * 128);
      asm volatile("s_waitcnt vmcnt(6)" ::: "memory");
    } else {
      asm volatile("s_waitcnt vmcnt(0)" ::: "memory");
    }
    SCHED0();
    #pragma unroll
    for (int q = 0; q < 4; ++q) *(int4*)(Abuf + aLds[q]) = rA1[q];
    #pragma unroll
    for (int q = 0; q < 2; ++q) *(int4*)(Braw + bLds[q]) = rB1[q];
    asm volatile("s_waitcnt lgkmcnt(0)" ::: "memory");
    SCHED0();
    __builtin_amdgcn_s_barrier();
    compute(tt + 1);
    if (tt + 2 < NK) {
      __builtin_amdgcn_s_barrier();
      SCHED0();
      if (tt + 3 < NK) {
        #pragma unroll
        for (int q = 0; q < 4; ++q) rA1[q] = *(const int4*)(aSrc[q] + (tt + 3) * 128);
        #pragma unroll
        for (int q = 0; q < 2; ++q) rB1[q] = *(const int4*)(bSrc[q] + (tt + 3) * 128);
        asm volatile("s_waitcnt vmcnt(6)" ::: "memory");
      } else {
        asm volatile("s_waitcnt vmcnt(0)" ::: "memory");
      }
      SCHED0();
      #pragma unroll
      for (int q = 0; q < 4; ++q) *(int4*)(Abuf + aLds[q]) = rA0[q];
      #pragma unroll
      for (int q = 0; q < 2; ++q) *(int4*)(Braw + bLds[q]) = rB0[q];
      asm volatile("s_waitcnt lgkmcnt(0)" ::: "memory");
      SCHED0();
      __builtin_amdgcn_s_barrier();
    }
  }

  #pragma unroll
  for (int fm = 0; fm < 2; ++fm) {
    #pragma unroll
    for (int rg = 0; rg < 4; ++rg) {
      int mloc = w * 32 + fm * 16 + kg * 4 + rg;
      if (mloc < n_valid) {
        int entry = s_tok[mloc];
        int t2 = entry >> 3, j = entry & 7;
        size_t slot = (size_t)t2 * kk + j;
        #pragma unroll
        for (int fn = 0; fn < 2; ++fn) {
          int h = hbase + fn * 16 + r15;
          partial[slot * HH + h] = (__bf16)acc[fm][fn][rg];
        }
      }
    }
  }
}

// ---------------- combine ----------------
__global__ void combine_kernel(const __bf16* __restrict__ partial, const float* __restrict__ route,
                               const float* __restrict__ dbias, const int* __restrict__ dk,
                               float* __restrict__ out, int E) {
  int t = blockIdx.y;
  int h = blockIdx.x * 256 + threadIdx.x;
  int kk = *dk; if (kk > KMAX) kk = KMAX; if (kk < 1) kk = 1;
  float s = 0.f;
  for (int j = 0; j < kk; ++j) s += (float)partial[((size_t)t * kk + j) * HH + h];
  for (int e = 0; e < E; ++e) s += route[t * E + e] * dbias[(size_t)e * HH + h];
  out[(size_t)t * HH + h] = s;
}

extern "C" void kernel_launch(void* const* d_in, const int* in_sizes, int n_in,
                              void* d_out, int out_size, void* d_ws, size_t ws_size,
                              hipStream_t stream) {
  const float* hs    = (const float*)d_in[0];
  const float* rl    = (const float*)d_in[1];
  const int*   gblk  = (const int*)d_in[2];
  const int*   gscl  = (const int*)d_in[3];
  const float* gbias = (const float*)d_in[4];
  const int*   ublk  = (const int*)d_in[5];
  const int*   uscl  = (const int*)d_in[6];
  const float* ubias = (const float*)d_in[7];
  const int*   dblk  = (const int*)d_in[8];
  const int*   dscl  = (const int*)d_in[9];
  const float* dbias = (const float*)d_in[10];
  const int*   dk    = (const int*)d_in[11];

  long s0 = in_sizes[0], s1 = in_sizes[1], s2 = in_sizes[2], s4 = in_sizes[4];
  int H = (int)(2 * s2 / s4);       // = 1024
  int T = (int)(s0 / H);            // = 1024
  int E = (int)(s1 / T);            // = 8

  char* w = (char*)d_ws;
  auto alloc = [&](size_t bytes) { char* p = w; w += (bytes + 255) & ~size_t(255); return p; };
  float*  route   = (float*)alloc(sizeof(float) * (size_t)T * E);
  float*  twp     = (float*)alloc(sizeof(float) * (size_t)T * KMAX);
  int*    counts  = (int*)  alloc(sizeof(int)   * (size_t)E);
  int*    lists   = (int*)  alloc(sizeof(int)   * (size_t)E * T);
  int*    tabGU   = (int*)  alloc(sizeof(int)   * GU_TILES);
  int*    tabDN   = (int*)  alloc(sizeof(int)   * DN_TILES);
  __bf16* hsb     = (__bf16*)alloc(sizeof(__bf16) * (size_t)T * HH);
  __bf16* act     = (__bf16*)alloc(sizeof(__bf16) * (size_t)T * KMAX * II);
  __bf16* partial = (__bf16*)alloc(sizeof(__bf16) * (size_t)T * KMAX * HH);

  int n8 = T * HH / 8;
  int nConv = (n8 + 1023) / 1024;
  prep_convert<<<dim3(nConv + 1), 1024, 0, stream>>>(
      rl, dk, T, E, route, twp, lists, counts, tabGU, tabDN, hs, hsb, n8);
  gemm_gate_up<<<dim3(GU_TILES * (II / 16)), 128, 0, stream>>>(
      hsb, gblk, gscl, gbias, ublk, uscl, ubias, lists, counts, twp, dk, tabGU, act, T);
  gemm_down<<<dim3(DN_TILES * (HH / 32)), 128, 0, stream>>>(
      act, dblk, dscl, lists, counts, dk, tabDN, partial, T);
  combine_kernel<<<dim3(HH / 256, T), 256, 0, stream>>>(partial, route, dbias, dk, (float*)d_out, E);
}

// Round 11
// 106.171 us; speedup vs baseline: 2.6148x; 2.6148x over previous
//
#include <hip/hip_runtime.h>
#include <cstdint>
#include <cstddef>

typedef __bf16 bf16x8 __attribute__((ext_vector_type(8)));
typedef __bf16 bf16x2 __attribute__((ext_vector_type(2)));
typedef float f32x16 __attribute__((ext_vector_type(16)));
typedef unsigned short u16x2 __attribute__((ext_vector_type(2)));

constexpr int HH = 1024;   // hidden dim
constexpr int II = 1024;   // intermediate dim
constexpr int KMAX = 2;
constexpr int EMAX = 8;
constexpr int GU_TILES = 40;   // M=64 tiles: worst case 32 + 8
constexpr int DN_TILES = 40;
constexpr float FALPHA = 1.702f;
constexpr float FLIMIT = 7.0f;

#if __has_builtin(__builtin_amdgcn_cvt_scalef32_pk_bf16_fp4)
#define USE_CVT 1
#else
#define USE_CVT 0
#endif

#define SCHED0() __builtin_amdgcn_sched_barrier(0)

// ---- fallback perm decode (k-order within 8-group permuted [0,2,4,6,1,3,5,7]) ----
__device__ __forceinline__ unsigned pk_add16(unsigned a, unsigned b) {
  u16x2 x, y;
  __builtin_memcpy(&x, &a, 4); __builtin_memcpy(&y, &b, 4);
  u16x2 r = x + y;
  unsigned o; __builtin_memcpy(&o, &r, 4); return o;
}
__device__ __forceinline__ int4 decode_chunk(int4 raw, unsigned addk) {
  unsigned p = (unsigned)raw.x | ((unsigned)raw.y << 8) |
               ((unsigned)raw.z << 16) | ((unsigned)raw.w << 24);
  unsigned q = p >> 4;
  unsigned me = p & 0x07070707u, mo = q & 0x07070707u;
  unsigned se = p & 0x08080808u, so = q & 0x08080808u;
  unsigned hiE = __builtin_amdgcn_perm(0x40404040u, 0x3F3F3F14u, me) | (se << 4);
  unsigned hiO = __builtin_amdgcn_perm(0x40404040u, 0x3F3F3F14u, mo) | (so << 4);
  unsigned loE = __builtin_amdgcn_perm(0xC0804000u, 0xC0800000u, me);
  unsigned loO = __builtin_amdgcn_perm(0xC0804000u, 0xC0800000u, mo);
  int4 out;
  out.x = (int)pk_add16(__builtin_amdgcn_perm(hiE, loE, 0x05010400u), addk);
  out.y = (int)pk_add16(__builtin_amdgcn_perm(hiE, loE, 0x07030602u), addk);
  out.z = (int)pk_add16(__builtin_amdgcn_perm(hiO, loO, 0x05010400u), addk);
  out.w = (int)pk_add16(__builtin_amdgcn_perm(hiO, loO, 0x07030602u), addk);
  return out;
}
__device__ __forceinline__ unsigned make_addk(int s) {
  int k = s - 127;
  unsigned t = ((unsigned)(k << 7)) & 0xFFFFu;
  return t | (t << 16);
}

// raw chunk (8 fp4 as int32-per-byte) + e8m0 scale -> bf16x8 fragment
__device__ __forceinline__ bf16x8 decode_frag(int4 raw, int s) {
#if USE_CVT
  unsigned t0 = __builtin_amdgcn_perm((unsigned)raw.y, (unsigned)raw.x, 0x00000400u);
  unsigned t1 = __builtin_amdgcn_perm((unsigned)raw.w, (unsigned)raw.z, 0x00000400u);
  unsigned p  = __builtin_amdgcn_perm(t1, t0, 0x05040100u);
  float scf = __uint_as_float((unsigned)s << 23);
  bf16x2 a = __builtin_amdgcn_cvt_scalef32_pk_bf16_fp4(p, scf, 0);
  bf16x2 b = __builtin_amdgcn_cvt_scalef32_pk_bf16_fp4(p, scf, 1);
  bf16x2 c = __builtin_amdgcn_cvt_scalef32_pk_bf16_fp4(p, scf, 2);
  bf16x2 d = __builtin_amdgcn_cvt_scalef32_pk_bf16_fp4(p, scf, 3);
  bf16x8 r;
  r[0]=a[0]; r[1]=a[1]; r[2]=b[0]; r[3]=b[1]; r[4]=c[0]; r[5]=c[1]; r[6]=d[0]; r[7]=d[1];
  return r;
#else
  int4 d4 = decode_chunk(raw, make_addk(s));
  bf16x8 r; __builtin_memcpy(&r, &d4, 16);
  return r;
#endif
}

__device__ __forceinline__ void gll16(const void* g, void* l) {
  __builtin_amdgcn_global_load_lds(
      (const __attribute__((address_space(1))) void*)g,
      (__attribute__((address_space(3))) void*)l, 16, 0, 0);
}

// bijective chunked XCD swizzle (m204)
__device__ __forceinline__ int xcd_swz(int wg, int nwg) {
  int q = nwg >> 3, r = nwg & 7;
  int xcd = wg & 7, pos = wg >> 3;
  return (xcd < r ? xcd * (q + 1) : r * (q + 1) + (xcd - r) * q) + pos;
}

// ---------------- fused prep + hs convert ----------------
__global__ __launch_bounds__(1024) void prep_convert(
    const float* __restrict__ logits, const int* __restrict__ dk, int T, int E,
    float* __restrict__ route, float* __restrict__ tw,
    int* __restrict__ lists, int* __restrict__ counts,
    int* __restrict__ tabGU, int* __restrict__ tabDN,
    const float* __restrict__ hs, __bf16* __restrict__ hsb, int n8) {
  if ((int)blockIdx.x < (int)gridDim.x - 1) {
    int g = blockIdx.x * 1024 + threadIdx.x;
    if (g < n8) {
      const float4* p = (const float4*)hs + (size_t)g * 2;
      float4 a = p[0], b = p[1];
      bf16x8 r;
#if USE_CVT
      r[0] = (__bf16)a.x; r[1] = (__bf16)a.y; r[2] = (__bf16)a.z; r[3] = (__bf16)a.w;
      r[4] = (__bf16)b.x; r[5] = (__bf16)b.y; r[6] = (__bf16)b.z; r[7] = (__bf16)b.w;
#else
      r[0] = (__bf16)a.x; r[1] = (__bf16)a.z; r[2] = (__bf16)b.x; r[3] = (__bf16)b.z;
      r[4] = (__bf16)a.y; r[5] = (__bf16)a.w; r[6] = (__bf16)b.y; r[7] = (__bf16)b.w;
#endif
      *(bf16x8*)(hsb + (size_t)g * 8) = r;
    }
    return;
  }
  __shared__ unsigned char s_ti[1024];
  __shared__ int s_cnt[EMAX];
  int t = threadIdx.x;
  int kk = *dk; if (kk > KMAX) kk = KMAX; if (kk < 1) kk = 1;
  int EE = E > EMAX ? EMAX : E;
  if (t < T) {
    float v[EMAX]; bool used[EMAX];
    for (int e = 0; e < EE; ++e) { v[e] = logits[t * E + e]; used[e] = false; route[t * E + e] = 0.f; }
    float tv[KMAX]; int ti[KMAX];
    for (int j = 0; j < kk; ++j) {
      float best = -3.4e38f; int bi = 0;
      for (int e = 0; e < EE; ++e) if (!used[e] && v[e] > best) { best = v[e]; bi = e; }
      used[bi] = true; tv[j] = best; ti[j] = bi;
    }
    float mx = tv[0], ssum = 0.f, wj[KMAX];
    for (int j = 0; j < kk; ++j) { wj[j] = __expf(tv[j] - mx); ssum += wj[j]; }
    for (int j = 0; j < kk; ++j) {
      float wv = wj[j] / ssum;
      route[t * E + ti[j]] = wv;
      tw[t * kk + j] = wv;
    }
    s_ti[t] = (unsigned char)(ti[0] | ((kk > 1 ? ti[1] : 0xF) << 4));
  } else if (t < 1024) {
    s_ti[t] = 0xFF;
  }
  __syncthreads();
  int w = t >> 6, lane = t & 63;
  if (w < EE) {
    int e = w, cnt = 0;
    for (int base = 0; base < T; base += 64) {
      int tt = base + lane;
      int j = -1;
      if (tt < T) {
        int packed = s_ti[tt];
        if ((packed & 0xF) == e) j = 0;
        else if ((packed >> 4) == e) j = 1;
      }
      unsigned long long m = __ballot(j >= 0);
      if (j >= 0) {
        int pre = __popcll(m & ((1ull << lane) - 1ull));
        lists[e * T + cnt + pre] = (tt << 3) | j;
      }
      cnt += __popcll(m);
    }
    if (lane == 0) { counts[e] = cnt; s_cnt[e] = cnt; }
  }
  __syncthreads();
  if (t == 0) {
    int g = 0, d = 0;
    for (int e = 0; e < EE; ++e) {
      int c = s_cnt[e];
      for (int m = 0; m * 64 < c && g < GU_TILES; ++m) tabGU[g++] = (e << 16) | m;
      for (int m = 0; m * 64 < c && d < DN_TILES; ++m) tabDN[d++] = (e << 16) | m;
    }
    for (; g < GU_TILES; ++g) tabGU[g] = -1;
    for (; d < DN_TILES; ++d) tabDN[d] = -1;
  }
}

// ================= gate+up GEMM: 32x32x16 MFMA =================
// Block: M=64 slots x N=64 cols (32 i x {gate,up}), BK=64, 128 thr = 2 waves.
// Wave w: all 64 M-rows x cols [w*32, w*32+32). Per step: 8 mfma_32x32x16, 12 ds_read_b128.
// gll16 staging, pre-swizzled source, depth-2 counted-vmcnt(8).
__global__ __launch_bounds__(128, 2) void gemm_gate_up(
    const __bf16* __restrict__ hsb,
    const int* __restrict__ gblk, const int* __restrict__ gscl, const float* __restrict__ gbias,
    const int* __restrict__ ublk, const int* __restrict__ uscl, const float* __restrict__ ubias,
    const int* __restrict__ lists, const int* __restrict__ counts,
    const float* __restrict__ tw, const int* __restrict__ dk,
    const int* __restrict__ tab,
    __bf16* __restrict__ act, int T)
{
  int lin = xcd_swz(blockIdx.x, GU_TILES * (II / 32));
  int ntile = lin / GU_TILES, xt = lin % GU_TILES;
  int te = tab[xt];
  if (te < 0) return;
  int e = te >> 16, mtile = te & 0xFFFF;
  int cnt = counts[e];
  int n_valid = cnt - mtile * 64;
  if (n_valid <= 0) return;
  if (n_valid > 64) n_valid = 64;
  int kk = *dk; if (kk > KMAX) kk = KMAX; if (kk < 1) kk = 1;
  int ibase = ntile * 32;

  __shared__ int s_tok[64];
  __shared__ __attribute__((aligned(16))) char Abuf[2][8192];  // 64 rows x 128B, [row][c^(row&7)]
  __shared__ __attribute__((aligned(16))) char Bbuf[2][8192];  // 64 rows raw fp4-inflated
  __shared__ __attribute__((aligned(8))) unsigned short sS[64][36];

  int tid = threadIdx.x;
  if (tid < 64) {
    int idx = mtile * 64 + tid;
    s_tok[tid] = lists[e * T + (idx < cnt ? idx : mtile * 64)];
  }
  __syncthreads();

  int lane = tid & 63, w = tid >> 6;
  int l31 = lane & 31, kg2 = lane >> 5;
  int sub = lane >> 3, cL = lane & 7;
  int cA = cL ^ (sub & 7);

  // A staging: wave w stages rows w*32 + q*8 + sub
  const char* aSrc[4];
  #pragma unroll
  for (int q = 0; q < 4; ++q) {
    int row = w * 32 + q * 8 + sub;
    int tok = s_tok[row] >> 3;
    aSrc[q] = (const char*)hsb + (size_t)tok * (HH * 2) + (size_t)cA * 16;
  }
  // B staging: row n (0..63): mat=(n>>4)&1, i = ibase + (n>>5)*16 + (n&15)
  const char* bSrc[4];
  #pragma unroll
  for (int q = 0; q < 4; ++q) {
    int row = w * 32 + q * 8 + sub;
    int mat = (row >> 4) & 1;
    int i = ibase + ((row >> 5) << 4) + (row & 15);
    const int* base = mat ? ublk : gblk;
    bSrc[q] = (const char*)(base + ((size_t)e * II + i) * (HH / 2)) + (size_t)cA * 16;
  }

  // ---- scales: 64 rows x 8 int4-chunks = 512 -> 4 per thread ----
  int4 sv4[4];
  #pragma unroll
  for (int rep = 0; rep < 4; ++rep) {
    int idx = tid + rep * 128;
    int row = idx >> 3, c4 = idx & 7;
    int mat = (row >> 4) & 1;
    int i = ibase + ((row >> 5) << 4) + (row & 15);
    const int* sbase = mat ? uscl : gscl;
    sv4[rep] = *((const int4*)(sbase + ((size_t)e * II + i) * 32) + c4);
  }
  asm volatile("s_waitcnt vmcnt(0)" ::: "memory");
  SCHED0();
  #pragma unroll
  for (int rep = 0; rep < 4; ++rep) {
    int idx = tid + rep * 128;
    int row = idx >> 3, c4 = idx & 7;
    unsigned short* dst = &sS[row][c4 * 4];
    dst[0] = (unsigned short)sv4[rep].x; dst[1] = (unsigned short)sv4[rep].y;
    dst[2] = (unsigned short)sv4[rep].z; dst[3] = (unsigned short)sv4[rep].w;
  }
  // ---- issue pipeline batches 0 and 1 (8 gll16/wave each) ----
  #pragma unroll
  for (int q = 0; q < 4; ++q) {
    gll16(aSrc[q], Abuf[0] + (w * 32 + q * 8) * 128);
    gll16(bSrc[q], Bbuf[0] + (w * 32 + q * 8) * 128);
  }
  #pragma unroll
  for (int q = 0; q < 4; ++q) {
    gll16(aSrc[q] + 128, Abuf[1] + (w * 32 + q * 8) * 128);
    gll16(bSrc[q] + 128, Bbuf[1] + (w * 32 + q * 8) * 128);
  }
  asm volatile("s_waitcnt vmcnt(8)" ::: "memory");     // batch0 landed
  asm volatile("s_waitcnt lgkmcnt(0)" ::: "memory");   // sS visible
  SCHED0();
  __builtin_amdgcn_s_barrier();
  SCHED0();

  f32x16 acc0 = (f32x16)0.f, acc1 = (f32x16)0.f;
  int brow = w * 32 + l31;

  constexpr int NK = HH / 64;  // 16
  #pragma unroll 1
  for (int t = 0; t < NK; ++t) {
    const char* Ac = Abuf[t & 1];
    const char* Bc = Bbuf[t & 1];
    unsigned sv = *(const unsigned*)((const char*)sS + brow * 72 + t * 4);
    #pragma unroll
    for (int s = 0; s < 4; ++s) {
      int kc = kg2 + 2 * s;
      int4 rawb = *(const int4*)(Bc + brow * 128 + ((kc ^ (brow & 7)) << 4));
      bf16x8 bb = decode_frag(rawb, (s >> 1) ? (int)(sv >> 16) : (int)(sv & 0xFFFF));
      bf16x8 a0 = *(const bf16x8*)(Ac + l31 * 128 + ((kc ^ (l31 & 7)) << 4));
      int m1 = l31 + 32;
      bf16x8 a1 = *(const bf16x8*)(Ac + m1 * 128 + ((kc ^ (m1 & 7)) << 4));
      acc0 = __builtin_amdgcn_mfma_f32_32x32x16_bf16(a0, bb, acc0, 0, 0, 0);
      acc1 = __builtin_amdgcn_mfma_f32_32x32x16_bf16(a1, bb, acc1, 0, 0, 0);
    }
    asm volatile("s_waitcnt lgkmcnt(0)" ::: "memory");
    SCHED0();
    __builtin_amdgcn_s_barrier();   // all waves done reading buf[t&1]
    SCHED0();
    if (t + 2 < NK) {
      char* An = Abuf[t & 1];
      char* Bn = Bbuf[t & 1];
      #pragma unroll
      for (int q = 0; q < 4; ++q) {
        gll16(aSrc[q] + (t + 2) * 128, An + (w * 32 + q * 8) * 128);
        gll16(bSrc[q] + (t + 2) * 128, Bn + (w * 32 + q * 8) * 128);
      }
      asm volatile("s_waitcnt vmcnt(8)" ::: "memory");   // batch t+1 landed
    } else {
      asm volatile("s_waitcnt vmcnt(0)" ::: "memory");
    }
    SCHED0();
    __builtin_amdgcn_s_barrier();
    SCHED0();
  }

  // ---- epilogue: col n pairs (n, n+16) = (gate, up) of i = ibase + w*16 + (n&15) ----
  {
    bool isGate = (l31 & 16) == 0;
    int i_log = ibase + w * 16 + (l31 & 15);
    float gb = gbias[e * II + i_log], ub = ubias[e * II + i_log];
#if USE_CVT
    int i_st = i_log;
#else
    int i_st = (i_log & ~7) | ((i_log & 1) << 2) | ((i_log & 7) >> 1);
#endif
    #pragma unroll
    for (int r = 0; r < 16; ++r) {
      float gv = acc0[r];
      float ov = __shfl_xor(gv, 16);
      int row = (r & 3) + 8 * (r >> 2) + 4 * kg2;
      if (isGate && row < n_valid) {
        int entry = s_tok[row];
        int t2 = entry >> 3, j = entry & 7;
        float wv = tw[t2 * kk + j];
        float g = fminf(gv + gb, FLIMIT);
        float u = fminf(fmaxf(ov + ub, -FLIMIT), FLIMIT);
        float glu = g / (1.f + __expf(-FALPHA * g));
        act[((size_t)t2 * kk + j) * II + i_st] = (__bf16)((u + 1.f) * glu * wv);
      }
    }
    #pragma unroll
    for (int r = 0; r < 16; ++r) {
      float gv = acc1[r];
      float ov = __shfl_xor(gv, 16);
      int row = (r & 3) + 8 * (r >> 2) + 4 * kg2 + 32;
      if (isGate && row < n_valid) {
        int entry = s_tok[row];
        int t2 = entry >> 3, j = entry & 7;
        float wv = tw[t2 * kk + j];
        float g = fminf(gv + gb, FLIMIT);
        float u = fminf(fmaxf(ov + ub, -FLIMIT), FLIMIT);
        float glu = g / (1.f + __expf(-FALPHA * g));
        act[((size_t)t2 * kk + j) * II + i_st] = (__bf16)((u + 1.f) * glu * wv);
      }
    }
  }
}

// ================= down GEMM: 32x32x16 MFMA =================
// Block: M=64 slots x N=64 h, BK=64, 128 thr = 2 waves; wave w: 64 rows x cols w*32..+31.
__global__ __launch_bounds__(128, 2) void gemm_down(
    const __bf16* __restrict__ act,
    const int* __restrict__ dblk, const int* __restrict__ dscl,
    const int* __restrict__ lists, const int* __restrict__ counts,
    const int* __restrict__ dk, const int* __restrict__ tab,
    __bf16* __restrict__ partial, int T)
{
  int lin = xcd_swz(blockIdx.x, DN_TILES * (HH / 64));
  int ntile = lin / DN_TILES, xt = lin % DN_TILES;
  int te = tab[xt];
  if (te < 0) return;
  int e = te >> 16, mtile = te & 0xFFFF;
  int cnt = counts[e];
  int n_valid = cnt - mtile * 64;
  if (n_valid <= 0) return;
  if (n_valid > 64) n_valid = 64;
  int kk = *dk; if (kk > KMAX) kk = KMAX; if (kk < 1) kk = 1;
  int hbase = ntile * 64;

  __shared__ int s_tok[64];
  __shared__ __attribute__((aligned(16))) char Abuf[2][8192];
  __shared__ __attribute__((aligned(16))) char Bbuf[2][8192];
  __shared__ __attribute__((aligned(8))) unsigned short sS[64][36];

  int tid = threadIdx.x;
  if (tid < 64) {
    int idx = mtile * 64 + tid;
    s_tok[tid] = lists[e * T + (idx < cnt ? idx : mtile * 64)];
  }
  __syncthreads();

  int lane = tid & 63, w = tid >> 6;
  int l31 = lane & 31, kg2 = lane >> 5;
  int sub = lane >> 3, cL = lane & 7;
  int cA = cL ^ (sub & 7);

  const char* aSrc[4];
  #pragma unroll
  for (int q = 0; q < 4; ++q) {
    int row = w * 32 + q * 8 + sub;
    int entry = s_tok[row];
    size_t slot = (size_t)(entry >> 3) * kk + (entry & 7);
    aSrc[q] = (const char*)act + slot * (II * 2) + (size_t)cA * 16;
  }
  const char* bSrc[4];
  #pragma unroll
  for (int q = 0; q < 4; ++q) {
    int row = w * 32 + q * 8 + sub;
    bSrc[q] = (const char*)(dblk + ((size_t)e * HH + hbase + row) * (II / 2)) + (size_t)cA * 16;
  }

  int4 sv4[4];
  #pragma unroll
  for (int rep = 0; rep < 4; ++rep) {
    int idx = tid + rep * 128;
    int row = idx >> 3, c4 = idx & 7;
    sv4[rep] = *((const int4*)(dscl + ((size_t)e * HH + hbase + row) * 32) + c4);
  }
  asm volatile("s_waitcnt vmcnt(0)" ::: "memory");
  SCHED0();
  #pragma unroll
  for (int rep = 0; rep < 4; ++rep) {
    int idx = tid + rep * 128;
    int row = idx >> 3, c4 = idx & 7;
    unsigned short* dst = &sS[row][c4 * 4];
    dst[0] = (unsigned short)sv4[rep].x; dst[1] = (unsigned short)sv4[rep].y;
    dst[2] = (unsigned short)sv4[rep].z; dst[3] = (unsigned short)sv4[rep].w;
  }
  #pragma unroll
  for (int q = 0; q < 4; ++q) {
    gll16(aSrc[q], Abuf[0] + (w * 32 + q * 8) * 128);
    gll16(bSrc[q], Bbuf[0] + (w * 32 + q * 8) * 128);
  }
  #pragma unroll
  for (int q = 0; q < 4; ++q) {
    gll16(aSrc[q] + 128, Abuf[1] + (w * 32 + q * 8) * 128);
    gll16(bSrc[q] + 128, Bbuf[1] + (w * 32 + q * 8) * 128);
  }
  asm volatile("s_waitcnt vmcnt(8)" ::: "memory");
  asm volatile("s_waitcnt lgkmcnt(0)" ::: "memory");
  SCHED0();
  __builtin_amdgcn_s_barrier();
  SCHED0();

  f32x16 acc0 = (f32x16)0.f, acc1 = (f32x16)0.f;
  int brow = w * 32 + l31;

  constexpr int NK = II / 64;  // 16
  #pragma unroll 1
  for (int t = 0; t < NK; ++t) {
    const char* Ac = Abuf[t & 1];
    const char* Bc = Bbuf[t & 1];
    unsigned sv = *(const unsigned*)((const char*)sS + brow * 72 + t * 4);
    #pragma unroll
    for (int s = 0; s < 4; ++s) {
      int kc = kg2 + 2 * s;
      int4 rawb = *(const int4*)(Bc + brow * 128 + ((kc ^ (brow & 7)) << 4));
      bf16x8 bb = decode_frag(rawb, (s >> 1) ? (int)(sv >> 16) : (int)(sv & 0xFFFF));
      bf16x8 a0 = *(const bf16x8*)(Ac + l31 * 128 + ((kc ^ (l31 & 7)) << 4));
      int m1 = l31 + 32;
      bf16x8 a1 = *(const bf16x8*)(Ac + m1 * 128 + ((kc ^ (m1 & 7)) << 4));
      acc0 = __builtin_amdgcn_mfma_f32_32x32x16_bf16(a0, bb, acc0, 0, 0, 0);
      acc1 = __builtin_amdgcn_mfma_f32_32x32x16_bf16(a1, bb, acc1, 0, 0, 0);
    }
    asm volatile("s_waitcnt lgkmcnt(0)" ::: "memory");
    SCHED0();
    __builtin_amdgcn_s_barrier();
    SCHED0();
    if (t + 2 < NK) {
      char* An = Abuf[t & 1];
      char* Bn = Bbuf[t & 1];
      #pragma unroll
      for (int q = 0; q < 4; ++q) {
        gll16(aSrc[q] + (t + 2) * 128, An + (w * 32 + q * 8) * 128);
        gll16(bSrc[q] + (t + 2) * 128, Bn + (w * 32 + q * 8) * 128);
      }
      asm volatile("s_waitcnt vmcnt(8)" ::: "memory");
    } else {
      asm volatile("s_waitcnt vmcnt(0)" ::: "memory");
    }
    SCHED0();
    __builtin_amdgcn_s_barrier();
    SCHED0();
  }

  // epilogue: h = hbase + w*32 + l31; rows via C layout
  {
    int h = hbase + w * 32 + l31;
    #pragma unroll
    for (int r = 0; r < 16; ++r) {
      int row = (r & 3) + 8 * (r >> 2) + 4 * kg2;
      if (row < n_valid) {
        int entry = s_tok[row];
        int t2 = entry >> 3, j = entry & 7;
        partial[((size_t)t2 * kk + j) * HH + h] = (__bf16)acc0[r];
      }
    }
    #pragma unroll
    for (int r = 0; r < 16; ++r) {
      int row = (r & 3) + 8 * (r >> 2) + 4 * kg2 + 32;
      if (row < n_valid) {
        int entry = s_tok[row];
        int t2 = entry >> 3, j = entry & 7;
        partial[((size_t)t2 * kk + j) * HH + h] = (__bf16)acc1[r];
      }
    }
  }
}

// ---------------- combine ----------------
__global__ void combine_kernel(const __bf16* __restrict__ partial, const float* __restrict__ route,
                               const float* __restrict__ dbias, const int* __restrict__ dk,
                               float* __restrict__ out, int E) {
  int t = blockIdx.y;
  int h = blockIdx.x * 256 + threadIdx.x;
  int kk = *dk; if (kk > KMAX) kk = KMAX; if (kk < 1) kk = 1;
  float s = 0.f;
  for (int j = 0; j < kk; ++j) s += (float)partial[((size_t)t * kk + j) * HH + h];
  for (int e = 0; e < E; ++e) s += route[t * E + e] * dbias[(size_t)e * HH + h];
  out[(size_t)t * HH + h] = s;
}

extern "C" void kernel_launch(void* const* d_in, const int* in_sizes, int n_in,
                              void* d_out, int out_size, void* d_ws, size_t ws_size,
                              hipStream_t stream) {
  const float* hs    = (const float*)d_in[0];
  const float* rl    = (const float*)d_in[1];
  const int*   gblk  = (const int*)d_in[2];
  const int*   gscl  = (const int*)d_in[3];
  const float* gbias = (const float*)d_in[4];
  const int*   ublk  = (const int*)d_in[5];
  const int*   uscl  = (const int*)d_in[6];
  const float* ubias = (const float*)d_in[7];
  const int*   dblk  = (const int*)d_in[8];
  const int*   dscl  = (const int*)d_in[9];
  const float* dbias = (const float*)d_in[10];
  const int*   dk    = (const int*)d_in[11];

  long s0 = in_sizes[0], s1 = in_sizes[1], s2 = in_sizes[2], s4 = in_sizes[4];
  int H = (int)(2 * s2 / s4);       // = 1024
  int T = (int)(s0 / H);            // = 1024
  int E = (int)(s1 / T);            // = 8

  char* w = (char*)d_ws;
  auto alloc = [&](size_t bytes) { char* p = w; w += (bytes + 255) & ~size_t(255); return p; };
  float*  route   = (float*)alloc(sizeof(float) * (size_t)T * E);
  float*  twp     = (float*)alloc(sizeof(float) * (size_t)T * KMAX);
  int*    counts  = (int*)  alloc(sizeof(int)   * (size_t)E);
  int*    lists   = (int*)  alloc(sizeof(int)   * (size_t)E * T);
  int*    tabGU   = (int*)  alloc(sizeof(int)   * GU_TILES);
  int*    tabDN   = (int*)  alloc(sizeof(int)   * DN_TILES);
  __bf16* hsb     = (__bf16*)alloc(sizeof(__bf16) * (size_t)T * HH);
  __bf16* act     = (__bf16*)alloc(sizeof(__bf16) * (size_t)T * KMAX * II);
  __bf16* partial = (__bf16*)alloc(sizeof(__bf16) * (size_t)T * KMAX * HH);

  int n8 = T * HH / 8;
  int nConv = (n8 + 1023) / 1024;
  prep_convert<<<dim3(nConv + 1), 1024, 0, stream>>>(
      rl, dk, T, E, route, twp, lists, counts, tabGU, tabDN, hs, hsb, n8);
  gemm_gate_up<<<dim3(GU_TILES * (II / 32)), 128, 0, stream>>>(
      hsb, gblk, gscl, gbias, ublk, uscl, ubias, lists, counts, twp, dk, tabGU, act, T);
  gemm_down<<<dim3(DN_TILES * (HH / 64)), 128, 0, stream>>>(
      act, dblk, dscl, lists, counts, dk, tabDN, partial, T);
  combine_kernel<<<dim3(HH / 256, T), 256, 0, stream>>>(partial, route, dbias, dk, (float*)d_out, E);
}

// Round 12
// 96.223 us; speedup vs baseline: 2.8851x; 1.1034x over previous
//
#include <hip/hip_runtime.h>
#include <cstdint>
#include <cstddef>

typedef __bf16 bf16x8 __attribute__((ext_vector_type(8)));
typedef __bf16 bf16x2 __attribute__((ext_vector_type(2)));
typedef float f32x16 __attribute__((ext_vector_type(16)));
typedef unsigned short u16x2 __attribute__((ext_vector_type(2)));

constexpr int HH = 1024;   // hidden dim
constexpr int II = 1024;   // intermediate dim
constexpr int KMAX = 2;
constexpr int EMAX = 8;
constexpr int GU_TILES = 24;   // M=128 tiles: worst case 16 + 8
constexpr int DN_TILES = 40;   // M=64 tiles: worst case 32 + 8
constexpr float FALPHA = 1.702f;
constexpr float FLIMIT = 7.0f;

#if __has_builtin(__builtin_amdgcn_cvt_scalef32_pk_bf16_fp4)
#define USE_CVT 1
#else
#define USE_CVT 0
#endif

#define SCHED0() __builtin_amdgcn_sched_barrier(0)

// ---- fallback perm decode (k-order within 8-group permuted [0,2,4,6,1,3,5,7]) ----
__device__ __forceinline__ unsigned pk_add16(unsigned a, unsigned b) {
  u16x2 x, y;
  __builtin_memcpy(&x, &a, 4); __builtin_memcpy(&y, &b, 4);
  u16x2 r = x + y;
  unsigned o; __builtin_memcpy(&o, &r, 4); return o;
}
__device__ __forceinline__ int4 decode_chunk(int4 raw, unsigned addk) {
  unsigned p = (unsigned)raw.x | ((unsigned)raw.y << 8) |
               ((unsigned)raw.z << 16) | ((unsigned)raw.w << 24);
  unsigned q = p >> 4;
  unsigned me = p & 0x07070707u, mo = q & 0x07070707u;
  unsigned se = p & 0x08080808u, so = q & 0x08080808u;
  unsigned hiE = __builtin_amdgcn_perm(0x40404040u, 0x3F3F3F14u, me) | (se << 4);
  unsigned hiO = __builtin_amdgcn_perm(0x40404040u, 0x3F3F3F14u, mo) | (so << 4);
  unsigned loE = __builtin_amdgcn_perm(0xC0804000u, 0xC0800000u, me);
  unsigned loO = __builtin_amdgcn_perm(0xC0804000u, 0xC0800000u, mo);
  int4 out;
  out.x = (int)pk_add16(__builtin_amdgcn_perm(hiE, loE, 0x05010400u), addk);
  out.y = (int)pk_add16(__builtin_amdgcn_perm(hiE, loE, 0x07030602u), addk);
  out.z = (int)pk_add16(__builtin_amdgcn_perm(hiO, loO, 0x05010400u), addk);
  out.w = (int)pk_add16(__builtin_amdgcn_perm(hiO, loO, 0x07030602u), addk);
  return out;
}
__device__ __forceinline__ unsigned make_addk(int s) {
  int k = s - 127;
  unsigned t = ((unsigned)(k << 7)) & 0xFFFFu;
  return t | (t << 16);
}

// raw chunk (8 fp4 as int32-per-byte) + e8m0 scale -> bf16x8 fragment
__device__ __forceinline__ bf16x8 decode_frag(int4 raw, int s) {
#if USE_CVT
  unsigned t0 = __builtin_amdgcn_perm((unsigned)raw.y, (unsigned)raw.x, 0x00000400u);
  unsigned t1 = __builtin_amdgcn_perm((unsigned)raw.w, (unsigned)raw.z, 0x00000400u);
  unsigned p  = __builtin_amdgcn_perm(t1, t0, 0x05040100u);
  float scf = __uint_as_float((unsigned)s << 23);
  bf16x2 a = __builtin_amdgcn_cvt_scalef32_pk_bf16_fp4(p, scf, 0);
  bf16x2 b = __builtin_amdgcn_cvt_scalef32_pk_bf16_fp4(p, scf, 1);
  bf16x2 c = __builtin_amdgcn_cvt_scalef32_pk_bf16_fp4(p, scf, 2);
  bf16x2 d = __builtin_amdgcn_cvt_scalef32_pk_bf16_fp4(p, scf, 3);
  bf16x8 r;
  r[0]=a[0]; r[1]=a[1]; r[2]=b[0]; r[3]=b[1]; r[4]=c[0]; r[5]=c[1]; r[6]=d[0]; r[7]=d[1];
  return r;
#else
  int4 d4 = decode_chunk(raw, make_addk(s));
  bf16x8 r; __builtin_memcpy(&r, &d4, 16);
  return r;
#endif
}

__device__ __forceinline__ void gll16(const void* g, void* l) {
  __builtin_amdgcn_global_load_lds(
      (const __attribute__((address_space(1))) void*)g,
      (__attribute__((address_space(3))) void*)l, 16, 0, 0);
}

// bijective chunked XCD swizzle (m204)
__device__ __forceinline__ int xcd_swz(int wg, int nwg) {
  int q = nwg >> 3, r = nwg & 7;
  int xcd = wg & 7, pos = wg >> 3;
  return (xcd < r ? xcd * (q + 1) : r * (q + 1) + (xcd - r) * q) + pos;
}

// ---------------- fused prep + hs convert ----------------
__global__ __launch_bounds__(1024) void prep_convert(
    const float* __restrict__ logits, const int* __restrict__ dk, int T, int E,
    float* __restrict__ route, float* __restrict__ tw,
    int* __restrict__ lists, int* __restrict__ counts,
    int* __restrict__ tabGU, int* __restrict__ tabDN,
    const float* __restrict__ hs, __bf16* __restrict__ hsb, int n8) {
  if ((int)blockIdx.x < (int)gridDim.x - 1) {
    int g = blockIdx.x * 1024 + threadIdx.x;
    if (g < n8) {
      const float4* p = (const float4*)hs + (size_t)g * 2;
      float4 a = p[0], b = p[1];
      bf16x8 r;
#if USE_CVT
      r[0] = (__bf16)a.x; r[1] = (__bf16)a.y; r[2] = (__bf16)a.z; r[3] = (__bf16)a.w;
      r[4] = (__bf16)b.x; r[5] = (__bf16)b.y; r[6] = (__bf16)b.z; r[7] = (__bf16)b.w;
#else
      r[0] = (__bf16)a.x; r[1] = (__bf16)a.z; r[2] = (__bf16)b.x; r[3] = (__bf16)b.z;
      r[4] = (__bf16)a.y; r[5] = (__bf16)a.w; r[6] = (__bf16)b.y; r[7] = (__bf16)b.w;
#endif
      *(bf16x8*)(hsb + (size_t)g * 8) = r;
    }
    return;
  }
  __shared__ unsigned char s_ti[1024];
  __shared__ int s_cnt[EMAX];
  int t = threadIdx.x;
  int kk = *dk; if (kk > KMAX) kk = KMAX; if (kk < 1) kk = 1;
  int EE = E > EMAX ? EMAX : E;
  if (t < T) {
    float v[EMAX]; bool used[EMAX];
    for (int e = 0; e < EE; ++e) { v[e] = logits[t * E + e]; used[e] = false; route[t * E + e] = 0.f; }
    float tv[KMAX]; int ti[KMAX];
    for (int j = 0; j < kk; ++j) {
      float best = -3.4e38f; int bi = 0;
      for (int e = 0; e < EE; ++e) if (!used[e] && v[e] > best) { best = v[e]; bi = e; }
      used[bi] = true; tv[j] = best; ti[j] = bi;
    }
    float mx = tv[0], ssum = 0.f, wj[KMAX];
    for (int j = 0; j < kk; ++j) { wj[j] = __expf(tv[j] - mx); ssum += wj[j]; }
    for (int j = 0; j < kk; ++j) {
      float wv = wj[j] / ssum;
      route[t * E + ti[j]] = wv;
      tw[t * kk + j] = wv;
    }
    s_ti[t] = (unsigned char)(ti[0] | ((kk > 1 ? ti[1] : 0xF) << 4));
  } else if (t < 1024) {
    s_ti[t] = 0xFF;
  }
  __syncthreads();
  int w = t >> 6, lane = t & 63;
  if (w < EE) {
    int e = w, cnt = 0;
    for (int base = 0; base < T; base += 64) {
      int tt = base + lane;
      int j = -1;
      if (tt < T) {
        int packed = s_ti[tt];
        if ((packed & 0xF) == e) j = 0;
        else if ((packed >> 4) == e) j = 1;
      }
      unsigned long long m = __ballot(j >= 0);
      if (j >= 0) {
        int pre = __popcll(m & ((1ull << lane) - 1ull));
        lists[e * T + cnt + pre] = (tt << 3) | j;
      }
      cnt += __popcll(m);
    }
    if (lane == 0) { counts[e] = cnt; s_cnt[e] = cnt; }
  }
  __syncthreads();
  if (t == 0) {
    int g = 0, d = 0;
    for (int e = 0; e < EE; ++e) {
      int c = s_cnt[e];
      for (int m = 0; m * 128 < c && g < GU_TILES; ++m) tabGU[g++] = (e << 16) | m;
      for (int m = 0; m * 64 < c && d < DN_TILES; ++m) tabDN[d++] = (e << 16) | m;
    }
    for (; g < GU_TILES; ++g) tabGU[g] = -1;
    for (; d < DN_TILES; ++d) tabDN[d] = -1;
  }
}

// ================= gate+up GEMM: M=128 x N=128, 8 waves, 32x32x16 MFMA =================
// Wave w: wr=w>>2 (row half 64), wc=w&3 (col group 32). Per wave-step: 8 MFMA, 12 ds_read_b128.
// Staging: each wave 2 A-rows-groups + 2 B-rows-groups = 4 gll16/batch, vmcnt(4) depth-2.
__global__ __launch_bounds__(512, 2) void gemm_gate_up(
    const __bf16* __restrict__ hsb,
    const int* __restrict__ gblk, const int* __restrict__ gscl, const float* __restrict__ gbias,
    const int* __restrict__ ublk, const int* __restrict__ uscl, const float* __restrict__ ubias,
    const int* __restrict__ lists, const int* __restrict__ counts,
    const float* __restrict__ tw, const int* __restrict__ dk,
    const int* __restrict__ tab,
    __bf16* __restrict__ act, int T)
{
  int lin = xcd_swz(blockIdx.x, GU_TILES * (II / 64));
  int ntile = lin / GU_TILES, xt = lin % GU_TILES;
  int te = tab[xt];
  if (te < 0) return;
  int e = te >> 16, mtile = te & 0xFFFF;
  int cnt = counts[e];
  int n_valid = cnt - mtile * 128;
  if (n_valid <= 0) return;
  if (n_valid > 128) n_valid = 128;
  int kk = *dk; if (kk > KMAX) kk = KMAX; if (kk < 1) kk = 1;
  int ibase = ntile * 64;

  __shared__ int s_tok[128];
  __shared__ __attribute__((aligned(16))) char Abuf[2][16384];  // 128 rows x 128B, [row][c^(row&7)]
  __shared__ __attribute__((aligned(16))) char Bbuf[2][16384];  // 128 rows raw fp4-inflated
  __shared__ __attribute__((aligned(8))) unsigned short sS[128][36];

  int tid = threadIdx.x;
  if (tid < 128) {
    int idx = mtile * 128 + tid;
    s_tok[tid] = lists[e * T + (idx < cnt ? idx : mtile * 128)];
  }
  __syncthreads();

  int lane = tid & 63, w = tid >> 6;     // 8 waves
  int wr = w >> 2, wc = w & 3;
  int l31 = lane & 31, kg2 = lane >> 5;
  int sub = lane >> 3, cL = lane & 7;
  int cA = cL ^ (sub & 7);

  // staging: wave w covers A rows [w*16, w*16+16) and B rows [w*16, w*16+16)
  const char* aSrc[2];
  #pragma unroll
  for (int q = 0; q < 2; ++q) {
    int row = w * 16 + q * 8 + sub;
    int tok = s_tok[row] >> 3;
    aSrc[q] = (const char*)hsb + (size_t)tok * (HH * 2) + (size_t)cA * 16;
  }
  const char* bSrc[2];
  #pragma unroll
  for (int q = 0; q < 2; ++q) {
    int row = w * 16 + q * 8 + sub;            // B row n: mat=(n>>4)&1, i=ibase+(n>>5)*16+(n&15)
    int mat = (row >> 4) & 1;
    int i = ibase + ((row >> 5) << 4) + (row & 15);
    const int* base = mat ? ublk : gblk;
    bSrc[q] = (const char*)(base + ((size_t)e * II + i) * (HH / 2)) + (size_t)cA * 16;
  }

  // scales: 128 rows x 8 int4-chunks = 1024 -> 2 per thread
  int4 sv4[2];
  #pragma unroll
  for (int rep = 0; rep < 2; ++rep) {
    int idx = tid + rep * 512;
    int row = idx >> 3, c4 = idx & 7;
    int mat = (row >> 4) & 1;
    int i = ibase + ((row >> 5) << 4) + (row & 15);
    const int* sbase = mat ? uscl : gscl;
    sv4[rep] = *((const int4*)(sbase + ((size_t)e * II + i) * 32) + c4);
  }
  asm volatile("s_waitcnt vmcnt(0)" ::: "memory");
  SCHED0();
  #pragma unroll
  for (int rep = 0; rep < 2; ++rep) {
    int idx = tid + rep * 512;
    int row = idx >> 3, c4 = idx & 7;
    unsigned short* dst = &sS[row][c4 * 4];
    dst[0] = (unsigned short)sv4[rep].x; dst[1] = (unsigned short)sv4[rep].y;
    dst[2] = (unsigned short)sv4[rep].z; dst[3] = (unsigned short)sv4[rep].w;
  }
  // issue pipeline batches 0 and 1 (4 gll16/wave each)
  #pragma unroll
  for (int q = 0; q < 2; ++q) {
    gll16(aSrc[q], Abuf[0] + (w * 16 + q * 8) * 128);
    gll16(bSrc[q], Bbuf[0] + (w * 16 + q * 8) * 128);
  }
  #pragma unroll
  for (int q = 0; q < 2; ++q) {
    gll16(aSrc[q] + 128, Abuf[1] + (w * 16 + q * 8) * 128);
    gll16(bSrc[q] + 128, Bbuf[1] + (w * 16 + q * 8) * 128);
  }
  asm volatile("s_waitcnt vmcnt(4)" ::: "memory");     // batch0 landed
  asm volatile("s_waitcnt lgkmcnt(0)" ::: "memory");   // sS visible
  SCHED0();
  __builtin_amdgcn_s_barrier();
  SCHED0();

  f32x16 acc0 = (f32x16)0.f, acc1 = (f32x16)0.f;
  int brow = wc * 32 + l31;

  constexpr int NK = HH / 64;  // 16
  #pragma unroll 1
  for (int t = 0; t < NK; ++t) {
    const char* Ac = Abuf[t & 1];
    const char* Bc = Bbuf[t & 1];
    unsigned sv = *(const unsigned*)((const char*)sS + brow * 72 + t * 4);
    #pragma unroll
    for (int s = 0; s < 4; ++s) {
      int kc = kg2 + 2 * s;
      int4 rawb = *(const int4*)(Bc + brow * 128 + ((kc ^ (brow & 7)) << 4));
      bf16x8 bb = decode_frag(rawb, (s >> 1) ? (int)(sv >> 16) : (int)(sv & 0xFFFF));
      int m0 = wr * 64 + l31;
      bf16x8 a0 = *(const bf16x8*)(Ac + m0 * 128 + ((kc ^ (m0 & 7)) << 4));
      int m1 = m0 + 32;
      bf16x8 a1 = *(const bf16x8*)(Ac + m1 * 128 + ((kc ^ (m1 & 7)) << 4));
      acc0 = __builtin_amdgcn_mfma_f32_32x32x16_bf16(a0, bb, acc0, 0, 0, 0);
      acc1 = __builtin_amdgcn_mfma_f32_32x32x16_bf16(a1, bb, acc1, 0, 0, 0);
    }
    asm volatile("s_waitcnt lgkmcnt(0)" ::: "memory");
    SCHED0();
    __builtin_amdgcn_s_barrier();   // all waves done reading buf[t&1]
    SCHED0();
    if (t + 2 < NK) {
      char* An = Abuf[t & 1];
      char* Bn = Bbuf[t & 1];
      #pragma unroll
      for (int q = 0; q < 2; ++q) {
        gll16(aSrc[q] + (t + 2) * 128, An + (w * 16 + q * 8) * 128);
        gll16(bSrc[q] + (t + 2) * 128, Bn + (w * 16 + q * 8) * 128);
      }
      asm volatile("s_waitcnt vmcnt(4)" ::: "memory");   // batch t+1 landed
    } else {
      asm volatile("s_waitcnt vmcnt(0)" ::: "memory");
    }
    SCHED0();
    __builtin_amdgcn_s_barrier();
    SCHED0();
  }

  // epilogue: col pairs (n, n^16) = (gate, up) of i = ibase + wc*16 + (l31&15)
  {
    bool isGate = (l31 & 16) == 0;
    int i_log = ibase + wc * 16 + (l31 & 15);
    float gb = gbias[e * II + i_log], ub = ubias[e * II + i_log];
#if USE_CVT
    int i_st = i_log;
#else
    int i_st = (i_log & ~7) | ((i_log & 1) << 2) | ((i_log & 7) >> 1);
#endif
    #pragma unroll
    for (int r = 0; r < 16; ++r) {
      float gv = acc0[r];
      float ov = __shfl_xor(gv, 16);
      int row = wr * 64 + (r & 3) + 8 * (r >> 2) + 4 * kg2;
      if (isGate && row < n_valid) {
        int entry = s_tok[row];
        int t2 = entry >> 3, j = entry & 7;
        float wv = tw[t2 * kk + j];
        float g = fminf(gv + gb, FLIMIT);
        float u = fminf(fmaxf(ov + ub, -FLIMIT), FLIMIT);
        float glu = g / (1.f + __expf(-FALPHA * g));
        act[((size_t)t2 * kk + j) * II + i_st] = (__bf16)((u + 1.f) * glu * wv);
      }
    }
    #pragma unroll
    for (int r = 0; r < 16; ++r) {
      float gv = acc1[r];
      float ov = __shfl_xor(gv, 16);
      int row = wr * 64 + (r & 3) + 8 * (r >> 2) + 4 * kg2 + 32;
      if (isGate && row < n_valid) {
        int entry = s_tok[row];
        int t2 = entry >> 3, j = entry & 7;
        float wv = tw[t2 * kk + j];
        float g = fminf(gv + gb, FLIMIT);
        float u = fminf(fmaxf(ov + ub, -FLIMIT), FLIMIT);
        float glu = g / (1.f + __expf(-FALPHA * g));
        act[((size_t)t2 * kk + j) * II + i_st] = (__bf16)((u + 1.f) * glu * wv);
      }
    }
  }
}

// ================= down GEMM: M=64 x N=128, 8 waves, 32x32x16 MFMA =================
// Wave w: wr=w>>2 (row half 32), wc=w&3 (col group 32). 3 gll16/batch, vmcnt(3).
__global__ __launch_bounds__(512, 2) void gemm_down(
    const __bf16* __restrict__ act,
    const int* __restrict__ dblk, const int* __restrict__ dscl,
    const int* __restrict__ lists, const int* __restrict__ counts,
    const int* __restrict__ dk, const int* __restrict__ tab,
    __bf16* __restrict__ partial, int T)
{
  int lin = xcd_swz(blockIdx.x, DN_TILES * (HH / 128));
  int ntile = lin / DN_TILES, xt = lin % DN_TILES;
  int te = tab[xt];
  if (te < 0) return;
  int e = te >> 16, mtile = te & 0xFFFF;
  int cnt = counts[e];
  int n_valid = cnt - mtile * 64;
  if (n_valid <= 0) return;
  if (n_valid > 64) n_valid = 64;
  int kk = *dk; if (kk > KMAX) kk = KMAX; if (kk < 1) kk = 1;
  int hbase = ntile * 128;

  __shared__ int s_tok[64];
  __shared__ __attribute__((aligned(16))) char Abuf[2][8192];   // 64 rows
  __shared__ __attribute__((aligned(16))) char Bbuf[2][16384];  // 128 rows
  __shared__ __attribute__((aligned(8))) unsigned short sS[128][36];

  int tid = threadIdx.x;
  if (tid < 64) {
    int idx = mtile * 64 + tid;
    s_tok[tid] = lists[e * T + (idx < cnt ? idx : mtile * 64)];
  }
  __syncthreads();

  int lane = tid & 63, w = tid >> 6;
  int wr = w >> 2, wc = w & 3;
  int l31 = lane & 31, kg2 = lane >> 5;
  int sub = lane >> 3, cL = lane & 7;
  int cA = cL ^ (sub & 7);

  // staging: wave w covers A rows [w*8, w*8+8) (1 gll16) and B rows [w*16, w*16+16) (2 gll16)
  const char* aSrc0;
  {
    int row = w * 8 + sub;
    int entry = s_tok[row];
    size_t slot = (size_t)(entry >> 3) * kk + (entry & 7);
    aSrc0 = (const char*)act + slot * (II * 2) + (size_t)cA * 16;
  }
  const char* bSrc[2];
  #pragma unroll
  for (int q = 0; q < 2; ++q) {
    int row = w * 16 + q * 8 + sub;
    bSrc[q] = (const char*)(dblk + ((size_t)e * HH + hbase + row) * (II / 2)) + (size_t)cA * 16;
  }

  int4 sv4[2];
  #pragma unroll
  for (int rep = 0; rep < 2; ++rep) {
    int idx = tid + rep * 512;
    int row = idx >> 3, c4 = idx & 7;
    sv4[rep] = *((const int4*)(dscl + ((size_t)e * HH + hbase + row) * 32) + c4);
  }
  asm volatile("s_waitcnt vmcnt(0)" ::: "memory");
  SCHED0();
  #pragma unroll
  for (int rep = 0; rep < 2; ++rep) {
    int idx = tid + rep * 512;
    int row = idx >> 3, c4 = idx & 7;
    unsigned short* dst = &sS[row][c4 * 4];
    dst[0] = (unsigned short)sv4[rep].x; dst[1] = (unsigned short)sv4[rep].y;
    dst[2] = (unsigned short)sv4[rep].z; dst[3] = (unsigned short)sv4[rep].w;
  }
  {
    gll16(aSrc0, Abuf[0] + (w * 8) * 128);
    #pragma unroll
    for (int q = 0; q < 2; ++q) gll16(bSrc[q], Bbuf[0] + (w * 16 + q * 8) * 128);
    gll16(aSrc0 + 128, Abuf[1] + (w * 8) * 128);
    #pragma unroll
    for (int q = 0; q < 2; ++q) gll16(bSrc[q] + 128, Bbuf[1] + (w * 16 + q * 8) * 128);
  }
  asm volatile("s_waitcnt vmcnt(3)" ::: "memory");
  asm volatile("s_waitcnt lgkmcnt(0)" ::: "memory");
  SCHED0();
  __builtin_amdgcn_s_barrier();
  SCHED0();

  f32x16 acc0 = (f32x16)0.f;
  int brow = wc * 32 + l31;
  int m0 = wr * 32 + l31;

  constexpr int NK = II / 64;  // 16
  #pragma unroll 1
  for (int t = 0; t < NK; ++t) {
    const char* Ac = Abuf[t & 1];
    const char* Bc = Bbuf[t & 1];
    unsigned sv = *(const unsigned*)((const char*)sS + brow * 72 + t * 4);
    #pragma unroll
    for (int s = 0; s < 4; ++s) {
      int kc = kg2 + 2 * s;
      int4 rawb = *(const int4*)(Bc + brow * 128 + ((kc ^ (brow & 7)) << 4));
      bf16x8 bb = decode_frag(rawb, (s >> 1) ? (int)(sv >> 16) : (int)(sv & 0xFFFF));
      bf16x8 a0 = *(const bf16x8*)(Ac + m0 * 128 + ((kc ^ (m0 & 7)) << 4));
      acc0 = __builtin_amdgcn_mfma_f32_32x32x16_bf16(a0, bb, acc0, 0, 0, 0);
    }
    asm volatile("s_waitcnt lgkmcnt(0)" ::: "memory");
    SCHED0();
    __builtin_amdgcn_s_barrier();
    SCHED0();
    if (t + 2 < NK) {
      char* An = Abuf[t & 1];
      char* Bn = Bbuf[t & 1];
      gll16(aSrc0 + (t + 2) * 128, An + (w * 8) * 128);
      #pragma unroll
      for (int q = 0; q < 2; ++q)
        gll16(bSrc[q] + (t + 2) * 128, Bn + (w * 16 + q * 8) * 128);
      asm volatile("s_waitcnt vmcnt(3)" ::: "memory");
    } else {
      asm volatile("s_waitcnt vmcnt(0)" ::: "memory");
    }
    SCHED0();
    __builtin_amdgcn_s_barrier();
    SCHED0();
  }

  // epilogue: h = hbase + wc*32 + l31; rows = wr*32 + crow
  {
    int h = hbase + wc * 32 + l31;
    #pragma unroll
    for (int r = 0; r < 16; ++r) {
      int row = wr * 32 + (r & 3) + 8 * (r >> 2) + 4 * kg2;
      if (row < n_valid) {
        int entry = s_tok[row];
        int t2 = entry >> 3, j = entry & 7;
        partial[((size_t)t2 * kk + j) * HH + h] = (__bf16)acc0[r];
      }
    }
  }
}

// ---------------- combine ----------------
__global__ void combine_kernel(const __bf16* __restrict__ partial, const float* __restrict__ route,
                               const float* __restrict__ dbias, const int* __restrict__ dk,
                               float* __restrict__ out, int E) {
  int t = blockIdx.y;
  int h = blockIdx.x * 256 + threadIdx.x;
  int kk = *dk; if (kk > KMAX) kk = KMAX; if (kk < 1) kk = 1;
  float s = 0.f;
  for (int j = 0; j < kk; ++j) s += (float)partial[((size_t)t * kk + j) * HH + h];
  for (int e = 0; e < E; ++e) s += route[t * E + e] * dbias[(size_t)e * HH + h];
  out[(size_t)t * HH + h] = s;
}

extern "C" void kernel_launch(void* const* d_in, const int* in_sizes, int n_in,
                              void* d_out, int out_size, void* d_ws, size_t ws_size,
                              hipStream_t stream) {
  const float* hs    = (const float*)d_in[0];
  const float* rl    = (const float*)d_in[1];
  const int*   gblk  = (const int*)d_in[2];
  const int*   gscl  = (const int*)d_in[3];
  const float* gbias = (const float*)d_in[4];
  const int*   ublk  = (const int*)d_in[5];
  const int*   uscl  = (const int*)d_in[6];
  const float* ubias = (const float*)d_in[7];
  const int*   dblk  = (const int*)d_in[8];
  const int*   dscl  = (const int*)d_in[9];
  const float* dbias = (const float*)d_in[10];
  const int*   dk    = (const int*)d_in[11];

  long s0 = in_sizes[0], s1 = in_sizes[1], s2 = in_sizes[2], s4 = in_sizes[4];
  int H = (int)(2 * s2 / s4);       // = 1024
  int T = (int)(s0 / H);            // = 1024
  int E = (int)(s1 / T);            // = 8

  char* w = (char*)d_ws;
  auto alloc = [&](size_t bytes) { char* p = w; w += (bytes + 255) & ~size_t(255); return p; };
  float*  route   = (float*)alloc(sizeof(float) * (size_t)T * E);
  float*  twp     = (float*)alloc(sizeof(float) * (size_t)T * KMAX);
  int*    counts  = (int*)  alloc(sizeof(int)   * (size_t)E);
  int*    lists   = (int*)  alloc(sizeof(int)   * (size_t)E * T);
  int*    tabGU   = (int*)  alloc(sizeof(int)   * GU_TILES);
  int*    tabDN   = (int*)  alloc(sizeof(int)   * DN_TILES);
  __bf16* hsb     = (__bf16*)alloc(sizeof(__bf16) * (size_t)T * HH);
  __bf16* act     = (__bf16*)alloc(sizeof(__bf16) * (size_t)T * KMAX * II);
  __bf16* partial = (__bf16*)alloc(sizeof(__bf16) * (size_t)T * KMAX * HH);

  int n8 = T * HH / 8;
  int nConv = (n8 + 1023) / 1024;
  prep_convert<<<dim3(nConv + 1), 1024, 0, stream>>>(
      rl, dk, T, E, route, twp, lists, counts, tabGU, tabDN, hs, hsb, n8);
  gemm_gate_up<<<dim3(GU_TILES * (II / 64)), 512, 0, stream>>>(
      hsb, gblk, gscl, gbias, ublk, uscl, ubias, lists, counts, twp, dk, tabGU, act, T);
  gemm_down<<<dim3(DN_TILES * (HH / 128)), 512, 0, stream>>>(
      act, dblk, dscl, lists, counts, dk, tabDN, partial, T);
  combine_kernel<<<dim3(HH / 256, T), 256, 0, stream>>>(partial, route, dbias, dk, (float*)d_out, E);
}